// Round 1
// baseline (3886.439 us; speedup 1.0000x reference)
//
#include <hip/hip_runtime.h>

#define B_    2
#define T_    8192
#define D_    256
#define E_    8
#define TWOD  512
#define NTOK  16384
#define CAP_  2048
#define NQ    (NTOK * 128)   // number of float4 in an (N, 512) fp32 array

// ---------------- init: x_states = x, x_target = phase_targets(x) ----------------
__global__ __launch_bounds__(256) void init_kernel(const float4* __restrict__ x,
    const float* __restrict__ cosp, const float* __restrict__ sinp,
    float4* __restrict__ xt, float4* __restrict__ xs)
{
  int q = blockIdx.x * 256 + threadIdx.x;
  if (q >= NQ) return;
  int n = q >> 7, dq = q & 127, t = n & (T_ - 1);
  float4 v = x[q];
  xs[q] = v;
  float4 g;
  if (t == 0) {
    g = v;
  } else {
    float4 p = x[q - 128];
    int d0 = dq * 2;
    float c0 = cosp[d0], s0 = sinp[d0], c1 = cosp[d0 + 1], s1 = sinp[d0 + 1];
    g.x = p.x * c0 - p.y * s0;
    g.y = p.x * s0 + p.y * c0;
    g.z = p.z * c1 - p.w * s1;
    g.w = p.z * s1 + p.w * c1;
  }
  xt[q] = g;
}

// ---------------- delays: x_eff = x + sum_tau complex(g_tau) * shift(x, tau) ----
__global__ __launch_bounds__(256) void delays_kernel(const float4* __restrict__ xs,
    const float* __restrict__ gains, float4* __restrict__ xe)
{
  int q = blockIdx.x * 256 + threadIdx.x;
  if (q >= NQ) return;
  int n = q >> 7, dq = q & 127, t = n & (T_ - 1);
  float4 v = xs[q];
  const int taus[4] = {1, 2, 3, 5};
  int d0 = dq * 2;
  #pragma unroll
  for (int i = 0; i < 4; i++) {
    int tau = taus[i];
    if (t >= tau) {
      float4 p = xs[q - tau * 128];
      float gr0 = gains[(i * D_ + d0) * 2 + 0], gi0 = gains[(i * D_ + d0) * 2 + 1];
      float gr1 = gains[(i * D_ + d0 + 1) * 2 + 0], gi1 = gains[(i * D_ + d0 + 1) * 2 + 1];
      v.x += p.x * gr0 - p.y * gi0;
      v.y += p.x * gi0 + p.y * gr0;
      v.z += p.z * gr1 - p.w * gi1;
      v.w += p.z * gi1 + p.w * gr1;
    }
  }
  xe[q] = v;
}

// ---------------- gate: scoresT[e][n] = softmax_e(xf[n] @ gate_w) ----------------
__global__ __launch_bounds__(64) void gate_kernel(const float4* __restrict__ xe,
    const float* __restrict__ gw, float* __restrict__ scoresT)
{
  int n = blockIdx.x;
  int lane = threadIdx.x;
  float4 a0 = xe[n * 128 + lane * 2];
  float4 a1 = xe[n * 128 + lane * 2 + 1];
  float av[8] = {a0.x, a0.y, a0.z, a0.w, a1.x, a1.y, a1.z, a1.w};
  float p[8] = {0, 0, 0, 0, 0, 0, 0, 0};
  int k0 = lane * 8;
  #pragma unroll
  for (int j = 0; j < 8; j++) {
    const float* wrow = gw + (k0 + j) * 8;
    #pragma unroll
    for (int e = 0; e < 8; e++) p[e] = fmaf(av[j], wrow[e], p[e]);
  }
  #pragma unroll
  for (int off = 32; off > 0; off >>= 1) {
    #pragma unroll
    for (int e = 0; e < 8; e++) p[e] += __shfl_down(p[e], off);
  }
  if (lane == 0) {
    float m = p[0];
    #pragma unroll
    for (int e = 1; e < 8; e++) m = fmaxf(m, p[e]);
    float s = 0.f, ex[8];
    #pragma unroll
    for (int e = 0; e < 8; e++) { ex[e] = expf(p[e] - m); s += ex[e]; }
    #pragma unroll
    for (int e = 0; e < 8; e++) scoresT[e * NTOK + n] = ex[e] / s;
  }
}

// ---------------- exact top-2048 per expert (radix select, index tie-break) ------
__global__ __launch_bounds__(256) void select_kernel(const float* __restrict__ scoresT,
    int* __restrict__ idxl, float* __restrict__ vall, int* __restrict__ counts)
{
  int e = blockIdx.x;
  const float* s = scoresT + (size_t)e * NTOK;
  int tid = threadIdx.x;
  __shared__ int hist[256];
  __shared__ int red[256];
  __shared__ int sh_b, sh_k, sh_cnt;

  unsigned prefix = 0;
  int k = CAP_;
  for (int p = 0; p < 4; ++p) {
    int shift = 24 - 8 * p;
    hist[tid] = 0;
    __syncthreads();
    for (int n = tid; n < NTOK; n += 256) {
      unsigned u = __float_as_uint(s[n]);
      bool match = (p == 0) || ((u >> (shift + 8)) == prefix);
      if (match) atomicAdd(&hist[(u >> shift) & 255], 1);
    }
    __syncthreads();
    if (tid == 0) {
      int acc = 0, b = 255;
      for (; b > 0; --b) {
        if (acc + hist[b] >= k) break;
        acc += hist[b];
      }
      sh_b = b; sh_k = k - acc;
    }
    __syncthreads();
    prefix = (prefix << 8) | (unsigned)sh_b;
    k = sh_k;
    __syncthreads();
  }
  unsigned thr = prefix;

  // smallest C with count(u==thr && n<C) >= k  (lowest-index tie break, JAX semantics)
  int lo = 0, hi = NTOK;
  while (lo < hi) {
    int mid = (lo + hi) >> 1;
    int c = 0;
    for (int n = tid; n < mid; n += 256) c += (__float_as_uint(s[n]) == thr) ? 1 : 0;
    red[tid] = c; __syncthreads();
    for (int off = 128; off > 0; off >>= 1) { if (tid < off) red[tid] += red[tid + off]; __syncthreads(); }
    int total = red[0];
    __syncthreads();
    if (total >= k) hi = mid; else lo = mid + 1;
  }
  int C = lo;

  if (tid == 0) sh_cnt = 0;
  __syncthreads();
  for (int n = tid; n < NTOK; n += 256) {
    unsigned u = __float_as_uint(s[n]);
    bool take = (u > thr) || (u == thr && n < C);
    if (take) {
      int slot = atomicAdd(&sh_cnt, 1);
      idxl[e * CAP_ + slot] = n;
      vall[e * CAP_ + slot] = s[n];
      atomicAdd(&counts[n], 1);
    }
  }
}

// ---------------- per-expert fp32 GEMM + scaled scatter into pred ----------------
#define BM 64
#define BN 64
#define BK 32
__global__ __launch_bounds__(256) void gemm_scatter_kernel(const float* __restrict__ xe,
    const float* __restrict__ ew, const int* __restrict__ idxl,
    const float* __restrict__ vall, float* __restrict__ pred)
{
  int bid = blockIdx.x;
  int e = bid >> 8, rem = bid & 255, mt = rem >> 3, nt = rem & 7;
  __shared__ float As[BM][BK + 4];   // 64 x 36 (float4-aligned rows)
  __shared__ float Bs[BK][BN];       // 32 x 64
  __shared__ int   rowtok[BM];
  __shared__ float rowval[BM];
  int tid = threadIdx.x;
  if (tid < BM) {
    rowtok[tid] = idxl[e * CAP_ + mt * BM + tid];
    rowval[tid] = vall[e * CAP_ + mt * BM + tid];
  }
  __syncthreads();
  int tx = tid & 15, ty = tid >> 4;
  const float* We = ew + (size_t)e * TWOD * TWOD + nt * BN;
  float acc[4][4] = {{0.f}};

  for (int kb = 0; kb < TWOD; kb += BK) {
    #pragma unroll
    for (int l = 0; l < 2; l++) {
      int id = tid + l * 256;
      int row = id >> 3, kc = id & 7;
      float4 a = *(const float4*)(xe + (size_t)rowtok[row] * TWOD + kb + kc * 4);
      *(float4*)(&As[row][kc * 4]) = a;
      int kk = id >> 4, fc = id & 15;
      float4 b = *(const float4*)(We + (size_t)(kb + kk) * TWOD + fc * 4);
      *(float4*)(&Bs[kk][fc * 4]) = b;
    }
    __syncthreads();
    #pragma unroll
    for (int k4 = 0; k4 < BK; k4 += 4) {
      float4 a4[4], b4[4];
      #pragma unroll
      for (int i = 0; i < 4; i++) a4[i] = *(const float4*)(&As[ty * 4 + i][k4]);
      #pragma unroll
      for (int u = 0; u < 4; u++) b4[u] = *(const float4*)(&Bs[k4 + u][tx * 4]);
      float ar[4][4], br[4][4];
      #pragma unroll
      for (int i = 0; i < 4; i++) {
        ar[i][0] = a4[i].x; ar[i][1] = a4[i].y; ar[i][2] = a4[i].z; ar[i][3] = a4[i].w;
      }
      #pragma unroll
      for (int u = 0; u < 4; u++) {
        br[u][0] = b4[u].x; br[u][1] = b4[u].y; br[u][2] = b4[u].z; br[u][3] = b4[u].w;
      }
      #pragma unroll
      for (int u = 0; u < 4; u++)
        #pragma unroll
        for (int i = 0; i < 4; i++)
          #pragma unroll
          for (int j = 0; j < 4; j++)
            acc[i][j] = fmaf(ar[i][u], br[u][j], acc[i][j]);
    }
    __syncthreads();
  }

  #pragma unroll
  for (int i = 0; i < 4; i++) {
    int row = ty * 4 + i;
    int token = rowtok[row];
    float val = rowval[row];
    float* pr = pred + (size_t)token * TWOD + nt * BN + tx * 4;
    #pragma unroll
    for (int j = 0; j < 4; j++) atomicAdd(&pr[j], val * acc[i][j]);
  }
}

// ---------------- x_states += lr * clip(x_target - pred, +-10) -------------------
__global__ __launch_bounds__(256) void update_kernel(const float4* __restrict__ xt,
    const float4* __restrict__ pred, float4* __restrict__ xs, float lr)
{
  int q = blockIdx.x * 256 + threadIdx.x;
  if (q >= NQ) return;
  float4 t = xt[q], p = pred[q], s = xs[q];
  s.x += lr * fminf(fmaxf(t.x - p.x, -10.f), 10.f);
  s.y += lr * fminf(fmaxf(t.y - p.y, -10.f), 10.f);
  s.z += lr * fminf(fmaxf(t.z - p.z, -10.f), 10.f);
  s.w += lr * fminf(fmaxf(t.w - p.w, -10.f), 10.f);
  xs[q] = s;
}

// ---------------- x_states = tanh(pred / max(counts,1) + bias) -------------------
__global__ __launch_bounds__(256) void activate_kernel(const float4* __restrict__ pred,
    const int* __restrict__ counts, const float4* __restrict__ bias, float4* __restrict__ xs)
{
  int q = blockIdx.x * 256 + threadIdx.x;
  if (q >= NQ) return;
  int n = q >> 7;
  float denom = fmaxf((float)counts[n], 1.0f);
  float4 p = pred[q];
  float4 b = bias[q & 127];
  float4 r;
  r.x = tanhf(p.x / denom + b.x);
  r.y = tanhf(p.y / denom + b.y);
  r.z = tanhf(p.z / denom + b.z);
  r.w = tanhf(p.w / denom + b.w);
  xs[q] = r;
}

// ---------------- out = xs + 0.5*(xt - pred); res_norm partial sums --------------
__global__ __launch_bounds__(256) void final_kernel(const float4* __restrict__ xt,
    const float4* __restrict__ pred, const float4* __restrict__ xs,
    float4* __restrict__ out, float* __restrict__ racc)
{
  int q = blockIdx.x * 256 + threadIdx.x;
  float lsum = 0.f;
  if (q < NQ) {
    float4 t = xt[q], p = pred[q], s = xs[q];
    float dr0 = t.x - p.x, di0 = t.y - p.y, dr1 = t.z - p.z, di1 = t.w - p.w;
    float4 o = {s.x + 0.5f * dr0, s.y + 0.5f * di0, s.z + 0.5f * dr1, s.w + 0.5f * di1};
    out[q] = o;
    lsum = sqrtf(dr0 * dr0 + di0 * di0) + sqrtf(dr1 * dr1 + di1 * di1);
  }
  __shared__ float red[256];
  red[threadIdx.x] = lsum;
  __syncthreads();
  for (int off = 128; off > 0; off >>= 1) {
    if (threadIdx.x < off) red[threadIdx.x] += red[threadIdx.x + off];
    __syncthreads();
  }
  if (threadIdx.x == 0) atomicAdd(racc, red[0]);
}

__global__ void finish_kernel(const float* __restrict__ racc, float* __restrict__ dst)
{
  if (threadIdx.x == 0) dst[0] = racc[0] / 4194304.0f;
}

// ---------------- host launch ----------------------------------------------------
extern "C" void kernel_launch(void* const* d_in, const int* in_sizes, int n_in,
                              void* d_out, int out_size, void* d_ws, size_t ws_size,
                              hipStream_t stream)
{
  const float* x     = (const float*)d_in[0];
  const float* gains = (const float*)d_in[1];
  const float* cosp  = (const float*)d_in[2];
  const float* sinp  = (const float*)d_in[3];
  const float* gw    = (const float*)d_in[4];
  const float* ew    = (const float*)d_in[5];
  const float* bias  = (const float*)d_in[6];
  float* out = (float*)d_out;

  char* w = (char*)d_ws;
  size_t off = 0;
  auto alloc = [&](size_t bytes) -> void* {
    void* p = w + off;
    off += (bytes + 255) & ~(size_t)255;
    return p;
  };
  float* xt      = (float*)alloc((size_t)NTOK * TWOD * 4);
  float* xs      = (float*)alloc((size_t)NTOK * TWOD * 4);
  float* xe      = (float*)alloc((size_t)NTOK * TWOD * 4);
  float* pred    = (float*)alloc((size_t)NTOK * TWOD * 4);
  float* scoresT = (float*)alloc((size_t)E_ * NTOK * 4);
  float* vall    = (float*)alloc((size_t)E_ * CAP_ * 4);
  int*   idxl    = (int*)  alloc((size_t)E_ * CAP_ * 4);
  int*   counts  = (int*)  alloc((size_t)NTOK * 4);
  float* racc    = (float*)alloc(256);

  const int eb = NQ / 256;  // 8192 blocks for elementwise float4 kernels

  init_kernel<<<eb, 256, 0, stream>>>((const float4*)x, cosp, sinp, (float4*)xt, (float4*)xs);

  double lr = 0.5;
  for (int it = 0; it < 9; ++it) {
    if (it == 8)
      activate_kernel<<<eb, 256, 0, stream>>>((const float4*)pred, counts,
                                              (const float4*)bias, (float4*)xs);
    delays_kernel<<<eb, 256, 0, stream>>>((const float4*)xs, gains, (float4*)xe);
    gate_kernel<<<NTOK, 64, 0, stream>>>((const float4*)xe, gw, scoresT);
    hipMemsetAsync(counts, 0, (size_t)NTOK * 4, stream);
    select_kernel<<<E_, 256, 0, stream>>>(scoresT, idxl, vall, counts);
    hipMemsetAsync(pred, 0, (size_t)NTOK * TWOD * 4, stream);
    gemm_scatter_kernel<<<E_ * 256, 256, 0, stream>>>(xe, ew, idxl, vall, pred);
    if (it < 8) {
      update_kernel<<<eb, 256, 0, stream>>>((const float4*)xt, (const float4*)pred,
                                            (float4*)xs, (float)lr);
      lr *= 0.85;
    }
  }
  hipMemsetAsync(racc, 0, 4, stream);
  final_kernel<<<eb, 256, 0, stream>>>((const float4*)xt, (const float4*)pred,
                                       (const float4*)xs, (float4*)out, racc);
  finish_kernel<<<1, 64, 0, stream>>>(racc, out + (size_t)NTOK * TWOD);
}

// Round 3
// 2712.913 us; speedup vs baseline: 1.4326x; 1.4326x over previous
//
#include <hip/hip_runtime.h>

#define T_    8192
#define D_    256
#define E_    8
#define TWOD  512
#define NTOK  16384
#define CAP_  2048
#define NQ    (NTOK * 128)   // float4 count of an (N, 512) fp32 array

// ---------------- init: x_states = x, x_target = phase_targets(x) ----------------
__global__ __launch_bounds__(256) void init_kernel(const float4* __restrict__ x,
    const float* __restrict__ cosp, const float* __restrict__ sinp,
    float4* __restrict__ xt, float4* __restrict__ xs)
{
  int q = blockIdx.x * 256 + threadIdx.x;
  int n = q >> 7, dq = q & 127, t = n & (T_ - 1);
  float4 v = x[q];
  xs[q] = v;
  float4 g;
  if (t == 0) {
    g = v;
  } else {
    float4 p = x[q - 128];
    int d0 = dq * 2;
    float c0 = cosp[d0], s0 = sinp[d0], c1 = cosp[d0 + 1], s1 = sinp[d0 + 1];
    g.x = p.x * c0 - p.y * s0;
    g.y = p.x * s0 + p.y * c0;
    g.z = p.z * c1 - p.w * s1;
    g.w = p.z * s1 + p.w * c1;
  }
  xt[q] = g;
}

// ---------------- delays + gate fused: xe + softmax scores ----------------------
__global__ __launch_bounds__(256) void delays_gate_kernel(const float4* __restrict__ xs,
    const float* __restrict__ gains, const float* __restrict__ gw,
    float4* __restrict__ xe, float* __restrict__ scoresT)
{
  int q = blockIdx.x * 256 + threadIdx.x;
  int n = q >> 7, dq = q & 127, t = n & (T_ - 1);
  float4 v = xs[q];
  const int taus[4] = {1, 2, 3, 5};
  int d0 = dq * 2;
  #pragma unroll
  for (int i = 0; i < 4; i++) {
    int tau = taus[i];
    if (t >= tau) {
      float4 p = xs[q - tau * 128];
      float gr0 = gains[(i * D_ + d0) * 2 + 0], gi0 = gains[(i * D_ + d0) * 2 + 1];
      float gr1 = gains[(i * D_ + d0 + 1) * 2 + 0], gi1 = gains[(i * D_ + d0 + 1) * 2 + 1];
      v.x += p.x * gr0 - p.y * gi0;
      v.y += p.x * gi0 + p.y * gr0;
      v.z += p.z * gr1 - p.w * gi1;
      v.w += p.z * gi1 + p.w * gr1;
    }
  }
  xe[q] = v;

  // gate partials: this thread covers k = dq*4 .. dq*4+3
  float p8[8] = {0, 0, 0, 0, 0, 0, 0, 0};
  const float4* gw4 = (const float4*)gw;
  float av[4] = {v.x, v.y, v.z, v.w};
  #pragma unroll
  for (int j = 0; j < 4; j++) {
    float4 w0 = gw4[(dq * 4 + j) * 2];
    float4 w1 = gw4[(dq * 4 + j) * 2 + 1];
    float a = av[j];
    p8[0] = fmaf(a, w0.x, p8[0]);
    p8[1] = fmaf(a, w0.y, p8[1]);
    p8[2] = fmaf(a, w0.z, p8[2]);
    p8[3] = fmaf(a, w0.w, p8[3]);
    p8[4] = fmaf(a, w1.x, p8[4]);
    p8[5] = fmaf(a, w1.y, p8[5]);
    p8[6] = fmaf(a, w1.z, p8[6]);
    p8[7] = fmaf(a, w1.w, p8[7]);
  }
  #pragma unroll
  for (int off = 32; off > 0; off >>= 1)
    #pragma unroll
    for (int e = 0; e < 8; e++) p8[e] += __shfl_down(p8[e], off);
  __shared__ float red[4][8];
  int wv = threadIdx.x >> 6;
  if ((threadIdx.x & 63) == 0)
    #pragma unroll
    for (int e = 0; e < 8; e++) red[wv][e] = p8[e];
  __syncthreads();
  if (threadIdx.x < 2) {
    int tok = blockIdx.x * 2 + threadIdx.x;
    float pe[8], m = -1e30f;
    #pragma unroll
    for (int e = 0; e < 8; e++) {
      pe[e] = red[threadIdx.x * 2][e] + red[threadIdx.x * 2 + 1][e];
      m = fmaxf(m, pe[e]);
    }
    float ssum = 0.f;
    #pragma unroll
    for (int e = 0; e < 8; e++) { pe[e] = expf(pe[e] - m); ssum += pe[e]; }
    float inv = 1.0f / ssum;
    #pragma unroll
    for (int e = 0; e < 8; e++) scoresT[e * NTOK + tok] = pe[e] * inv;
  }
}

// ---------------- exact top-2048 per expert: register-resident radix select -----
__global__ __launch_bounds__(1024) void select_kernel(const float* __restrict__ scoresT,
    int* __restrict__ idxl, int* __restrict__ slot_of)
{
  int e = blockIdx.x;
  const float* s = scoresT + (size_t)e * NTOK;
  int tid = threadIdx.x;
  int lane = tid & 63, wv = tid >> 6;   // 16 waves

  // load 16 values into registers: value r=j*4+c has index n = 4*tid + 4096*j + c
  float4 f[4];
  #pragma unroll
  for (int j = 0; j < 4; j++) f[j] = ((const float4*)s)[tid + 1024 * j];
  unsigned uv[16];
  #pragma unroll
  for (int j = 0; j < 4; j++) {
    uv[j * 4 + 0] = __float_as_uint(f[j].x);
    uv[j * 4 + 1] = __float_as_uint(f[j].y);
    uv[j * 4 + 2] = __float_as_uint(f[j].z);
    uv[j * 4 + 3] = __float_as_uint(f[j].w);
  }
  int nbase = tid * 4;

  __shared__ int hist[16][257];
  __shared__ int histsum[256];
  __shared__ int shB, shK, shTot, scnt;

  unsigned prefix = 0;
  int k = CAP_;
  for (int p = 0; p < 4; ++p) {
    int shift = 24 - 8 * p;
    for (int b = tid; b < 16 * 257; b += 1024) ((int*)hist)[b] = 0;
    __syncthreads();
    #pragma unroll
    for (int r = 0; r < 16; r++) {
      unsigned u = uv[r];
      bool match = (p == 0) || ((u >> (shift + 8)) == prefix);
      int b = (u >> shift) & 255;
      unsigned long long act = __ballot(match);
      while (act) {
        int src = __ffsll((long long)act) - 1;
        int b0 = __shfl(b, src);
        unsigned long long same = __ballot(match && b == b0);
        if (lane == src) hist[wv][b0] += __popcll(same);
        act &= ~same;
      }
    }
    __syncthreads();
    if (tid < 256) {
      int tsum = 0;
      #pragma unroll
      for (int w = 0; w < 16; w++) tsum += hist[w][tid];
      histsum[tid] = tsum;
    }
    __syncthreads();
    if (tid == 0) {
      int acc = 0, b = 255;
      for (; b > 0; --b) {
        int h = histsum[b];
        if (acc + h >= k) break;
        acc += h;
      }
      shB = b; shK = k - acc;
    }
    __syncthreads();
    prefix = (prefix << 8) | (unsigned)shB;
    k = shK;
    __syncthreads();
  }
  unsigned thr = prefix;

  // lowest-index tie break: smallest C with count(u==thr && n<C) >= k
  int lo = 0, hi = NTOK;
  while (lo < hi) {
    int mid = (lo + hi) >> 1;
    int c = 0;
    #pragma unroll
    for (int j = 0; j < 4; j++)
      #pragma unroll
      for (int cc = 0; cc < 4; cc++) {
        int n = nbase + 4096 * j + cc;
        c += (uv[j * 4 + cc] == thr && n < mid) ? 1 : 0;
      }
    #pragma unroll
    for (int off = 32; off > 0; off >>= 1) c += __shfl_down(c, off);
    if (lane == 0) histsum[wv] = c;
    __syncthreads();
    if (tid == 0) {
      int tot = 0;
      #pragma unroll
      for (int w = 0; w < 16; w++) tot += histsum[w];
      shTot = tot;
    }
    __syncthreads();
    if (shTot >= k) hi = mid; else lo = mid + 1;
    __syncthreads();
  }
  int C = lo;

  if (tid == 0) scnt = 0;
  __syncthreads();
  #pragma unroll
  for (int j = 0; j < 4; j++) {
    int4 so;
    int sov[4];
    #pragma unroll
    for (int cc = 0; cc < 4; cc++) {
      unsigned u = uv[j * 4 + cc];
      int n = nbase + 4096 * j + cc;
      bool take = (u > thr) || (u == thr && n < C);
      unsigned long long msk = __ballot(take);
      int cntw = __popcll(msk);
      int base = 0;
      if (lane == 0 && cntw) base = atomicAdd(&scnt, cntw);
      base = __shfl(base, 0);
      int slot = base + __popcll(msk & ((1ull << lane) - 1ull));
      int sv = -1;
      if (take) {
        idxl[e * CAP_ + slot] = n;
        sv = slot;
      }
      sov[cc] = sv;
    }
    so.x = sov[0]; so.y = sov[1]; so.z = sov[2]; so.w = sov[3];
    ((int4*)(slot_of + (size_t)e * NTOK))[tid + 1024 * j] = so;
  }
}

// ---------------- per-expert fp32 GEMM -> yo (no atomics) ------------------------
#define GM 128
#define GN 128
#define GKK 32
__device__ __forceinline__ float comp4(const float4 v, int u) {
  return u == 0 ? v.x : u == 1 ? v.y : u == 2 ? v.z : v.w;
}
__global__ __launch_bounds__(256) void gemm_kernel(const float* __restrict__ xe,
    const float* __restrict__ ew, const int* __restrict__ idxl, float* __restrict__ yo)
{
  int bid0 = blockIdx.x;
  // XCD swizzle: 512 blocks / 8 XCDs -> each XCD gets one expert (A panel 4MB, L2-fit)
  int bid = (bid0 & 7) * 64 + (bid0 >> 3);
  int e = bid >> 6, rem = bid & 63, mt = rem >> 2, nt = rem & 3;
  __shared__ float As[GM][GKK + 4];
  __shared__ float Bs[GKK][GN + 4];
  __shared__ int rowtok[GM];
  int tid = threadIdx.x;
  if (tid < GM) rowtok[tid] = idxl[e * CAP_ + mt * GM + tid];
  __syncthreads();
  int tx = tid & 15, ty = tid >> 4;
  const float* We = ew + (size_t)e * TWOD * TWOD + nt * GN;
  float acc[8][8] = {};

  for (int kb = 0; kb < TWOD; kb += GKK) {
    #pragma unroll
    for (int l = 0; l < 4; l++) {
      int id = tid + l * 256;
      int row = id >> 3, c4 = (id & 7) * 4;
      float4 a = *(const float4*)(xe + (size_t)rowtok[row] * TWOD + kb + c4);
      *(float4*)&As[row][c4] = a;
      int kk = id >> 5, cc = (id & 31) * 4;
      float4 b = *(const float4*)(We + (size_t)(kb + kk) * TWOD + cc);
      *(float4*)&Bs[kk][cc] = b;
    }
    __syncthreads();
    #pragma unroll
    for (int k4 = 0; k4 < GKK; k4 += 4) {
      float4 a4[8], b4[8];
      #pragma unroll
      for (int i = 0; i < 8; i++) a4[i] = *(const float4*)&As[ty * 8 + i][k4];
      #pragma unroll
      for (int u = 0; u < 4; u++) {
        b4[2 * u]     = *(const float4*)&Bs[k4 + u][tx * 8];
        b4[2 * u + 1] = *(const float4*)&Bs[k4 + u][tx * 8 + 4];
      }
      #pragma unroll
      for (int u = 0; u < 4; u++) {
        float av[8], bv[8];
        #pragma unroll
        for (int i = 0; i < 8; i++) av[i] = comp4(a4[i], u);
        bv[0] = b4[2*u].x; bv[1] = b4[2*u].y; bv[2] = b4[2*u].z; bv[3] = b4[2*u].w;
        bv[4] = b4[2*u+1].x; bv[5] = b4[2*u+1].y; bv[6] = b4[2*u+1].z; bv[7] = b4[2*u+1].w;
        #pragma unroll
        for (int i = 0; i < 8; i++)
          #pragma unroll
          for (int jj = 0; jj < 8; jj++)
            acc[i][jj] = fmaf(av[i], bv[jj], acc[i][jj]);
      }
    }
    __syncthreads();
  }
  #pragma unroll
  for (int i = 0; i < 8; i++) {
    float* dst = yo + (size_t)(e * CAP_ + mt * GM + ty * 8 + i) * TWOD + nt * GN + tx * 8;
    float4 o0 = {acc[i][0], acc[i][1], acc[i][2], acc[i][3]};
    float4 o1 = {acc[i][4], acc[i][5], acc[i][6], acc[i][7]};
    *(float4*)dst = o0;
    *(float4*)(dst + 4) = o1;
  }
}

// ---------------- combine (gather yo) + state update -----------------------------
__global__ __launch_bounds__(256) void combine_update_kernel(const float4* __restrict__ yo,
    const float* __restrict__ scoresT, const int* __restrict__ slot_of,
    const float4* __restrict__ xt, float4* __restrict__ xs,
    float4* __restrict__ pred, int* __restrict__ counts, float lr, int write_pred)
{
  int q = blockIdx.x * 256 + threadIdx.x;
  int n = q >> 7, dq = q & 127;
  float4 p = {0, 0, 0, 0};
  int cnt = 0;
  #pragma unroll
  for (int e = 0; e < E_; e++) {
    int sl = slot_of[e * NTOK + n];
    if (sl >= 0) {
      float val = scoresT[e * NTOK + n];
      float4 y = yo[(size_t)(e * CAP_ + sl) * 128 + dq];
      p.x = fmaf(val, y.x, p.x);
      p.y = fmaf(val, y.y, p.y);
      p.z = fmaf(val, y.z, p.z);
      p.w = fmaf(val, y.w, p.w);
      cnt++;
    }
  }
  float4 t = xt[q], s = xs[q];
  s.x += lr * fminf(fmaxf(t.x - p.x, -10.f), 10.f);
  s.y += lr * fminf(fmaxf(t.y - p.y, -10.f), 10.f);
  s.z += lr * fminf(fmaxf(t.z - p.z, -10.f), 10.f);
  s.w += lr * fminf(fmaxf(t.w - p.w, -10.f), 10.f);
  xs[q] = s;
  if (write_pred) {
    pred[q] = p;
    if (dq == 0) counts[n] = cnt;
  }
}

// ---------------- combine (gather yo) + final out + res partial -------------------
__global__ __launch_bounds__(256) void combine_final_kernel(const float4* __restrict__ yo,
    const float* __restrict__ scoresT, const int* __restrict__ slot_of,
    const float4* __restrict__ xt, const float4* __restrict__ xs,
    float4* __restrict__ out, float* __restrict__ racc)
{
  int q = blockIdx.x * 256 + threadIdx.x;
  int n = q >> 7, dq = q & 127;
  float4 p = {0, 0, 0, 0};
  #pragma unroll
  for (int e = 0; e < E_; e++) {
    int sl = slot_of[e * NTOK + n];
    if (sl >= 0) {
      float val = scoresT[e * NTOK + n];
      float4 y = yo[(size_t)(e * CAP_ + sl) * 128 + dq];
      p.x = fmaf(val, y.x, p.x);
      p.y = fmaf(val, y.y, p.y);
      p.z = fmaf(val, y.z, p.z);
      p.w = fmaf(val, y.w, p.w);
    }
  }
  float4 t = xt[q], s = xs[q];
  float dr0 = t.x - p.x, di0 = t.y - p.y, dr1 = t.z - p.z, di1 = t.w - p.w;
  float4 o = {s.x + 0.5f * dr0, s.y + 0.5f * di0, s.z + 0.5f * dr1, s.w + 0.5f * di1};
  out[q] = o;
  float lsum = sqrtf(dr0 * dr0 + di0 * di0) + sqrtf(dr1 * dr1 + di1 * di1);
  __shared__ float red[256];
  red[threadIdx.x] = lsum;
  __syncthreads();
  for (int off = 128; off > 0; off >>= 1) {
    if (threadIdx.x < off) red[threadIdx.x] += red[threadIdx.x + off];
    __syncthreads();
  }
  if (threadIdx.x == 0) atomicAdd(racc, red[0]);
}

// ---------------- x_states = tanh(pred / max(counts,1) + bias) -------------------
__global__ __launch_bounds__(256) void activate_kernel(const float4* __restrict__ pred,
    const int* __restrict__ counts, const float4* __restrict__ bias, float4* __restrict__ xs)
{
  int q = blockIdx.x * 256 + threadIdx.x;
  int n = q >> 7;
  float denom = fmaxf((float)counts[n], 1.0f);
  float4 p = pred[q];
  float4 b = bias[q & 127];
  float4 r;
  r.x = tanhf(p.x / denom + b.x);
  r.y = tanhf(p.y / denom + b.y);
  r.z = tanhf(p.z / denom + b.z);
  r.w = tanhf(p.w / denom + b.w);
  xs[q] = r;
}

__global__ void finish_kernel(const float* __restrict__ racc, float* __restrict__ dst)
{
  if (threadIdx.x == 0) dst[0] = racc[0] / 4194304.0f;
}

// ---------------- host launch ----------------------------------------------------
extern "C" void kernel_launch(void* const* d_in, const int* in_sizes, int n_in,
                              void* d_out, int out_size, void* d_ws, size_t ws_size,
                              hipStream_t stream)
{
  const float* x     = (const float*)d_in[0];
  const float* gains = (const float*)d_in[1];
  const float* cosp  = (const float*)d_in[2];
  const float* sinp  = (const float*)d_in[3];
  const float* gw    = (const float*)d_in[4];
  const float* ew    = (const float*)d_in[5];
  const float* bias  = (const float*)d_in[6];
  float* out = (float*)d_out;

  char* w = (char*)d_ws;
  size_t off = 0;
  auto alloc = [&](size_t bytes) -> void* {
    void* p = w + off;
    off += (bytes + 255) & ~(size_t)255;
    return p;
  };
  float* xt      = (float*)alloc((size_t)NTOK * TWOD * 4);
  float* xs      = (float*)alloc((size_t)NTOK * TWOD * 4);
  float* xe      = (float*)alloc((size_t)NTOK * TWOD * 4);
  float* pred    = (float*)alloc((size_t)NTOK * TWOD * 4);
  float* yo      = (float*)alloc((size_t)E_ * CAP_ * TWOD * 4);
  float* scoresT = (float*)alloc((size_t)E_ * NTOK * 4);
  int*   idxl    = (int*)  alloc((size_t)E_ * CAP_ * 4);
  int*   slot_of = (int*)  alloc((size_t)E_ * NTOK * 4);
  int*   counts  = (int*)  alloc((size_t)NTOK * 4);
  float* racc    = (float*)alloc(256);

  const int eb = NQ / 256;  // 8192

  init_kernel<<<eb, 256, 0, stream>>>((const float4*)x, cosp, sinp, (float4*)xt, (float4*)xs);

  double lr = 0.5;
  for (int it = 0; it < 9; ++it) {
    if (it == 8)
      activate_kernel<<<eb, 256, 0, stream>>>((const float4*)pred, counts,
                                              (const float4*)bias, (float4*)xs);
    delays_gate_kernel<<<eb, 256, 0, stream>>>((const float4*)xs, gains, gw,
                                               (float4*)xe, scoresT);
    select_kernel<<<E_, 1024, 0, stream>>>(scoresT, idxl, slot_of);
    gemm_kernel<<<512, 256, 0, stream>>>(xe, ew, idxl, yo);
    if (it < 8) {
      combine_update_kernel<<<eb, 256, 0, stream>>>((const float4*)yo, scoresT, slot_of,
          (const float4*)xt, (float4*)xs, (float4*)pred, counts, (float)lr, it == 7 ? 1 : 0);
      lr *= 0.85;
    } else {
      hipMemsetAsync(racc, 0, 4, stream);
      combine_final_kernel<<<eb, 256, 0, stream>>>((const float4*)yo, scoresT, slot_of,
          (const float4*)xt, (const float4*)xs, (float4*)out, racc);
    }
  }
  finish_kernel<<<1, 64, 0, stream>>>(racc, out + (size_t)NTOK * TWOD);
}

// Round 4
// 1899.780 us; speedup vs baseline: 2.0457x; 1.4280x over previous
//
#include <hip/hip_runtime.h>

#define T_    8192
#define D_    256
#define E_    8
#define TWOD  512
#define NTOK  16384
#define CAP_  2048
#define NQ    (NTOK * 128)   // float4 count of an (N, 512) fp32 array

// ---------------- init: x_states = x, x_target = phase_targets(x) ----------------
__global__ __launch_bounds__(256) void init_kernel(const float4* __restrict__ x,
    const float* __restrict__ cosp, const float* __restrict__ sinp,
    float4* __restrict__ xt, float4* __restrict__ xs)
{
  int q = blockIdx.x * 256 + threadIdx.x;
  int n = q >> 7, dq = q & 127, t = n & (T_ - 1);
  float4 v = x[q];
  xs[q] = v;
  float4 g;
  if (t == 0) {
    g = v;
  } else {
    float4 p = x[q - 128];
    int d0 = dq * 2;
    float c0 = cosp[d0], s0 = sinp[d0], c1 = cosp[d0 + 1], s1 = sinp[d0 + 1];
    g.x = p.x * c0 - p.y * s0;
    g.y = p.x * s0 + p.y * c0;
    g.z = p.z * c1 - p.w * s1;
    g.w = p.z * s1 + p.w * c1;
  }
  xt[q] = g;
}

// ---------------- delays + gate fused: xe + softmax scores ----------------------
__global__ __launch_bounds__(256) void delays_gate_kernel(const float4* __restrict__ xs,
    const float* __restrict__ gains, const float* __restrict__ gw,
    float4* __restrict__ xe, float* __restrict__ scoresT)
{
  int q = blockIdx.x * 256 + threadIdx.x;
  int n = q >> 7, dq = q & 127, t = n & (T_ - 1);
  float4 v = xs[q];
  const int taus[4] = {1, 2, 3, 5};
  int d0 = dq * 2;
  #pragma unroll
  for (int i = 0; i < 4; i++) {
    int tau = taus[i];
    if (t >= tau) {
      float4 p = xs[q - tau * 128];
      float gr0 = gains[(i * D_ + d0) * 2 + 0], gi0 = gains[(i * D_ + d0) * 2 + 1];
      float gr1 = gains[(i * D_ + d0 + 1) * 2 + 0], gi1 = gains[(i * D_ + d0 + 1) * 2 + 1];
      v.x += p.x * gr0 - p.y * gi0;
      v.y += p.x * gi0 + p.y * gr0;
      v.z += p.z * gr1 - p.w * gi1;
      v.w += p.z * gi1 + p.w * gr1;
    }
  }
  xe[q] = v;

  // gate partials: this thread covers k = dq*4 .. dq*4+3
  float p8[8] = {0, 0, 0, 0, 0, 0, 0, 0};
  const float4* gw4 = (const float4*)gw;
  float av[4] = {v.x, v.y, v.z, v.w};
  #pragma unroll
  for (int j = 0; j < 4; j++) {
    float4 w0 = gw4[(dq * 4 + j) * 2];
    float4 w1 = gw4[(dq * 4 + j) * 2 + 1];
    float a = av[j];
    p8[0] = fmaf(a, w0.x, p8[0]);
    p8[1] = fmaf(a, w0.y, p8[1]);
    p8[2] = fmaf(a, w0.z, p8[2]);
    p8[3] = fmaf(a, w0.w, p8[3]);
    p8[4] = fmaf(a, w1.x, p8[4]);
    p8[5] = fmaf(a, w1.y, p8[5]);
    p8[6] = fmaf(a, w1.z, p8[6]);
    p8[7] = fmaf(a, w1.w, p8[7]);
  }
  #pragma unroll
  for (int off = 32; off > 0; off >>= 1)
    #pragma unroll
    for (int e = 0; e < 8; e++) p8[e] += __shfl_down(p8[e], off);
  __shared__ float red[4][8];
  int wv = threadIdx.x >> 6;
  if ((threadIdx.x & 63) == 0)
    #pragma unroll
    for (int e = 0; e < 8; e++) red[wv][e] = p8[e];
  __syncthreads();
  if (threadIdx.x < 2) {
    int tok = blockIdx.x * 2 + threadIdx.x;
    float pe[8], m = -1e30f;
    #pragma unroll
    for (int e = 0; e < 8; e++) {
      pe[e] = red[threadIdx.x * 2][e] + red[threadIdx.x * 2 + 1][e];
      m = fmaxf(m, pe[e]);
    }
    float ssum = 0.f;
    #pragma unroll
    for (int e = 0; e < 8; e++) { pe[e] = expf(pe[e] - m); ssum += pe[e]; }
    float inv = 1.0f / ssum;
    #pragma unroll
    for (int e = 0; e < 8; e++) scoresT[e * NTOK + tok] = pe[e] * inv;
  }
}

// ---------------- exact top-2048 per expert: LDS-hist radix + scan tie-break -----
__global__ __launch_bounds__(1024) void select_kernel(const float* __restrict__ scoresT,
    int* __restrict__ idxl, int* __restrict__ slot_of)
{
  int e = blockIdx.x;
  const float* s = scoresT + (size_t)e * NTOK;
  int tid = threadIdx.x;
  int lane = tid & 63, wv = tid >> 6;   // 16 waves

  // load 16 values into registers: value r=j*4+cc has index n = 4*tid + 4096*j + cc
  float4 f[4];
  #pragma unroll
  for (int j = 0; j < 4; j++) f[j] = ((const float4*)s)[tid + 1024 * j];
  unsigned uv[16];
  #pragma unroll
  for (int j = 0; j < 4; j++) {
    uv[j * 4 + 0] = __float_as_uint(f[j].x);
    uv[j * 4 + 1] = __float_as_uint(f[j].y);
    uv[j * 4 + 2] = __float_as_uint(f[j].z);
    uv[j * 4 + 3] = __float_as_uint(f[j].w);
  }

  __shared__ int hist[16][257];
  __shared__ int histsum[256];
  __shared__ int sfx[2][256];
  __shared__ int wsum[16], wpre[16];
  __shared__ int shB, shK, shTot, scnt;

  unsigned prefix = 0;
  int k = CAP_;
  for (int p = 0; p < 4; ++p) {
    int shift = 24 - 8 * p;
    for (int b = tid; b < 16 * 257; b += 1024) ((int*)hist)[b] = 0;
    __syncthreads();
    #pragma unroll
    for (int r = 0; r < 16; r++) {
      unsigned u = uv[r];
      bool match = (p == 0) || ((u >> (shift + 8)) == prefix);
      if (match) atomicAdd(&hist[wv][(u >> shift) & 255], 1);
    }
    __syncthreads();
    if (tid < 256) {
      int tsum = 0;
      #pragma unroll
      for (int w = 0; w < 16; w++) tsum += hist[w][tid];
      histsum[tid] = tsum;
      sfx[0][tid] = tsum;
    }
    __syncthreads();
    // inclusive suffix sum over 256 buckets (Hillis-Steele, 8 steps)
    int cur = 0;
    #pragma unroll
    for (int d = 1; d < 256; d <<= 1) {
      if (tid < 256)
        sfx[cur ^ 1][tid] = sfx[cur][tid] + ((tid + d < 256) ? sfx[cur][tid + d] : 0);
      __syncthreads();
      cur ^= 1;
    }
    if (tid < 256) {
      int sv = sfx[cur][tid];
      int snext = (tid < 255) ? sfx[cur][tid + 1] : 0;
      if (sv >= k && snext < k) { shB = tid; shK = k - snext; }
    }
    __syncthreads();
    prefix = (prefix << 8) | (unsigned)shB;
    k = shK;
    __syncthreads();
  }
  unsigned thr = prefix;
  int kk = k;   // how many of the tied (== thr) values to take, lowest index first

  // ---- output: take = (u > thr) || (u == thr && index-rank among ties < kk) ----
  if (tid == 0) scnt = 0;
  __syncthreads();
  int jb = 0;   // tie-count base over j blocks (n-major ordering: j, then tid, then cc)
  #pragma unroll
  for (int j = 0; j < 4; j++) {
    int eqf[4], c = 0;
    #pragma unroll
    for (int cc = 0; cc < 4; cc++) {
      eqf[cc] = (uv[j * 4 + cc] == thr) ? 1 : 0;
      c += eqf[cc];
    }
    // wave inclusive scan of per-thread tie counts
    int sc = c;
    #pragma unroll
    for (int d = 1; d < 64; d <<= 1) {
      int tt = __shfl_up(sc, d);
      if (lane >= d) sc += tt;
    }
    if (lane == 63) wsum[wv] = sc;
    __syncthreads();
    if (tid == 0) {
      int a = 0;
      #pragma unroll
      for (int w = 0; w < 16; w++) { int t2 = wsum[w]; wpre[w] = a; a += t2; }
      shTot = a;
    }
    __syncthreads();
    int excl = wpre[wv] + (sc - c);   // exclusive prefix of ties for this thread
    int local = 0;
    int sov[4];
    #pragma unroll
    for (int cc = 0; cc < 4; cc++) {
      unsigned u = uv[j * 4 + cc];
      int n = 4 * tid + 4096 * j + cc;
      bool take = (u > thr) || (eqf[cc] && (jb + excl + local) < kk);
      local += eqf[cc];
      unsigned long long msk = __ballot(take);
      int cntw = __popcll(msk);
      int base = 0;
      if (lane == 0 && cntw) base = atomicAdd(&scnt, cntw);
      base = __shfl(base, 0);
      int slot = base + __popcll(msk & ((1ull << lane) - 1ull));
      int sv = -1;
      if (take) {
        idxl[e * CAP_ + slot] = n;
        sv = slot;
      }
      sov[cc] = sv;
    }
    int4 so;
    so.x = sov[0]; so.y = sov[1]; so.z = sov[2]; so.w = sov[3];
    ((int4*)(slot_of + (size_t)e * NTOK))[tid + 1024 * j] = so;
    jb += shTot;
    __syncthreads();
  }
}

// ---------------- per-expert fp32 GEMM -> yo (swizzled LDS, no conflicts) --------
#define GM 128
#define GN 128
#define GKK 32
__device__ __forceinline__ float comp4(const float4 v, int u) {
  return u == 0 ? v.x : u == 1 ? v.y : u == 2 ? v.z : v.w;
}
__global__ __launch_bounds__(256) void gemm_kernel(const float* __restrict__ xe,
    const float* __restrict__ ew, const int* __restrict__ idxl, float* __restrict__ yo)
{
  int bid0 = blockIdx.x;
  // XCD swizzle: 512 blocks / 8 XCDs -> each XCD gets one expert (A panel 4MB, L2-fit)
  int bid = (bid0 & 7) * 64 + (bid0 >> 3);
  int e = bid >> 6, rem = bid & 63, mt = rem >> 2, nt = rem & 3;
  __shared__ float4 As4[GM * 8];      // slot = row*8 + (kq ^ (row>>3 & 7))
  __shared__ float4 Bs4[GKK * 32];    // slot = k*32 + c   (c = col/4)
  __shared__ int rowtok[GM];
  int tid = threadIdx.x;
  if (tid < GM) rowtok[tid] = idxl[e * CAP_ + mt * GM + tid];
  __syncthreads();
  int tx = tid & 15, ty = tid >> 4;
  const float* We = ew + (size_t)e * TWOD * TWOD + nt * GN;
  float acc[8][8] = {};   // rows ty*8+i ; cols: jj<4 -> tx*4+jj, jj>=4 -> 64+tx*4+jj-4

  for (int kb = 0; kb < TWOD; kb += GKK) {
    #pragma unroll
    for (int l = 0; l < 4; l++) {
      int id = tid + l * 256;
      int row = id >> 3, kq = id & 7;
      float4 a = *(const float4*)(xe + (size_t)rowtok[row] * TWOD + kb + kq * 4);
      As4[row * 8 + (kq ^ ((row >> 3) & 7))] = a;
      int kkk = id >> 5, cc = id & 31;
      float4 b = *(const float4*)(We + (size_t)(kb + kkk) * TWOD + cc * 4);
      Bs4[kkk * 32 + cc] = b;
    }
    __syncthreads();
    #pragma unroll
    for (int k4 = 0; k4 < GKK; k4 += 4) {
      int kq = k4 >> 2;
      float4 a4[8], b4[8];
      #pragma unroll
      for (int i = 0; i < 8; i++) a4[i] = As4[(ty * 8 + i) * 8 + (kq ^ (ty & 7))];
      #pragma unroll
      for (int u = 0; u < 4; u++) {
        b4[2 * u]     = Bs4[(k4 + u) * 32 + tx];
        b4[2 * u + 1] = Bs4[(k4 + u) * 32 + 16 + tx];
      }
      #pragma unroll
      for (int u = 0; u < 4; u++) {
        float av[8], bv[8];
        #pragma unroll
        for (int i = 0; i < 8; i++) av[i] = comp4(a4[i], u);
        bv[0] = b4[2*u].x; bv[1] = b4[2*u].y; bv[2] = b4[2*u].z; bv[3] = b4[2*u].w;
        bv[4] = b4[2*u+1].x; bv[5] = b4[2*u+1].y; bv[6] = b4[2*u+1].z; bv[7] = b4[2*u+1].w;
        #pragma unroll
        for (int i = 0; i < 8; i++)
          #pragma unroll
          for (int jj = 0; jj < 8; jj++)
            acc[i][jj] = fmaf(av[i], bv[jj], acc[i][jj]);
      }
    }
    __syncthreads();
  }
  #pragma unroll
  for (int i = 0; i < 8; i++) {
    float* dst = yo + (size_t)(e * CAP_ + mt * GM + ty * 8 + i) * TWOD + nt * GN + tx * 4;
    float4 o0 = {acc[i][0], acc[i][1], acc[i][2], acc[i][3]};
    float4 o1 = {acc[i][4], acc[i][5], acc[i][6], acc[i][7]};
    *(float4*)dst = o0;
    *(float4*)(dst + 64) = o1;
  }
}

// ---------------- combine (gather yo) + state update -----------------------------
__global__ __launch_bounds__(256) void combine_update_kernel(const float4* __restrict__ yo,
    const float* __restrict__ scoresT, const int* __restrict__ slot_of,
    const float4* __restrict__ xt, float4* __restrict__ xs,
    float4* __restrict__ pred, int* __restrict__ counts, float lr, int write_pred)
{
  int q = blockIdx.x * 256 + threadIdx.x;
  int n = q >> 7, dq = q & 127;
  float4 p = {0, 0, 0, 0};
  int cnt = 0;
  #pragma unroll
  for (int e = 0; e < E_; e++) {
    int sl = slot_of[e * NTOK + n];
    if (sl >= 0) {
      float val = scoresT[e * NTOK + n];
      float4 y = yo[(size_t)(e * CAP_ + sl) * 128 + dq];
      p.x = fmaf(val, y.x, p.x);
      p.y = fmaf(val, y.y, p.y);
      p.z = fmaf(val, y.z, p.z);
      p.w = fmaf(val, y.w, p.w);
      cnt++;
    }
  }
  float4 t = xt[q], s = xs[q];
  s.x += lr * fminf(fmaxf(t.x - p.x, -10.f), 10.f);
  s.y += lr * fminf(fmaxf(t.y - p.y, -10.f), 10.f);
  s.z += lr * fminf(fmaxf(t.z - p.z, -10.f), 10.f);
  s.w += lr * fminf(fmaxf(t.w - p.w, -10.f), 10.f);
  xs[q] = s;
  if (write_pred) {
    pred[q] = p;
    if (dq == 0) counts[n] = cnt;
  }
}

// ---------------- combine (gather yo) + final out + res partial -------------------
__global__ __launch_bounds__(256) void combine_final_kernel(const float4* __restrict__ yo,
    const float* __restrict__ scoresT, const int* __restrict__ slot_of,
    const float4* __restrict__ xt, const float4* __restrict__ xs,
    float4* __restrict__ out, float* __restrict__ racc)
{
  int q = blockIdx.x * 256 + threadIdx.x;
  int n = q >> 7, dq = q & 127;
  float4 p = {0, 0, 0, 0};
  #pragma unroll
  for (int e = 0; e < E_; e++) {
    int sl = slot_of[e * NTOK + n];
    if (sl >= 0) {
      float val = scoresT[e * NTOK + n];
      float4 y = yo[(size_t)(e * CAP_ + sl) * 128 + dq];
      p.x = fmaf(val, y.x, p.x);
      p.y = fmaf(val, y.y, p.y);
      p.z = fmaf(val, y.z, p.z);
      p.w = fmaf(val, y.w, p.w);
    }
  }
  float4 t = xt[q], s = xs[q];
  float dr0 = t.x - p.x, di0 = t.y - p.y, dr1 = t.z - p.z, di1 = t.w - p.w;
  float4 o = {s.x + 0.5f * dr0, s.y + 0.5f * di0, s.z + 0.5f * dr1, s.w + 0.5f * di1};
  out[q] = o;
  float lsum = sqrtf(dr0 * dr0 + di0 * di0) + sqrtf(dr1 * dr1 + di1 * di1);
  __shared__ float red[256];
  red[threadIdx.x] = lsum;
  __syncthreads();
  for (int off = 128; off > 0; off >>= 1) {
    if (threadIdx.x < off) red[threadIdx.x] += red[threadIdx.x + off];
    __syncthreads();
  }
  if (threadIdx.x == 0) atomicAdd(racc, red[0]);
}

// ---------------- x_states = tanh(pred / max(counts,1) + bias) -------------------
__global__ __launch_bounds__(256) void activate_kernel(const float4* __restrict__ pred,
    const int* __restrict__ counts, const float4* __restrict__ bias, float4* __restrict__ xs)
{
  int q = blockIdx.x * 256 + threadIdx.x;
  int n = q >> 7;
  float denom = fmaxf((float)counts[n], 1.0f);
  float4 p = pred[q];
  float4 b = bias[q & 127];
  float4 r;
  r.x = tanhf(p.x / denom + b.x);
  r.y = tanhf(p.y / denom + b.y);
  r.z = tanhf(p.z / denom + b.z);
  r.w = tanhf(p.w / denom + b.w);
  xs[q] = r;
}

__global__ void finish_kernel(const float* __restrict__ racc, float* __restrict__ dst)
{
  if (threadIdx.x == 0) dst[0] = racc[0] / 4194304.0f;
}

// ---------------- host launch ----------------------------------------------------
extern "C" void kernel_launch(void* const* d_in, const int* in_sizes, int n_in,
                              void* d_out, int out_size, void* d_ws, size_t ws_size,
                              hipStream_t stream)
{
  const float* x     = (const float*)d_in[0];
  const float* gains = (const float*)d_in[1];
  const float* cosp  = (const float*)d_in[2];
  const float* sinp  = (const float*)d_in[3];
  const float* gw    = (const float*)d_in[4];
  const float* ew    = (const float*)d_in[5];
  const float* bias  = (const float*)d_in[6];
  float* out = (float*)d_out;

  char* w = (char*)d_ws;
  size_t off = 0;
  auto alloc = [&](size_t bytes) -> void* {
    void* p = w + off;
    off += (bytes + 255) & ~(size_t)255;
    return p;
  };
  float* xt      = (float*)alloc((size_t)NTOK * TWOD * 4);
  float* xs      = (float*)alloc((size_t)NTOK * TWOD * 4);
  float* xe      = (float*)alloc((size_t)NTOK * TWOD * 4);
  float* pred    = (float*)alloc((size_t)NTOK * TWOD * 4);
  float* yo      = (float*)alloc((size_t)E_ * CAP_ * TWOD * 4);
  float* scoresT = (float*)alloc((size_t)E_ * NTOK * 4);
  int*   idxl    = (int*)  alloc((size_t)E_ * CAP_ * 4);
  int*   slot_of = (int*)  alloc((size_t)E_ * NTOK * 4);
  int*   counts  = (int*)  alloc((size_t)NTOK * 4);
  float* racc    = (float*)alloc(256);

  const int eb = NQ / 256;  // 8192

  init_kernel<<<eb, 256, 0, stream>>>((const float4*)x, cosp, sinp, (float4*)xt, (float4*)xs);

  double lr = 0.5;
  for (int it = 0; it < 9; ++it) {
    if (it == 8)
      activate_kernel<<<eb, 256, 0, stream>>>((const float4*)pred, counts,
                                              (const float4*)bias, (float4*)xs);
    delays_gate_kernel<<<eb, 256, 0, stream>>>((const float4*)xs, gains, gw,
                                               (float4*)xe, scoresT);
    select_kernel<<<E_, 1024, 0, stream>>>(scoresT, idxl, slot_of);
    gemm_kernel<<<512, 256, 0, stream>>>(xe, ew, idxl, yo);
    if (it < 8) {
      combine_update_kernel<<<eb, 256, 0, stream>>>((const float4*)yo, scoresT, slot_of,
          (const float4*)xt, (float4*)xs, (float4*)pred, counts, (float)lr, it == 7 ? 1 : 0);
      lr *= 0.85;
    } else {
      hipMemsetAsync(racc, 0, 4, stream);
      combine_final_kernel<<<eb, 256, 0, stream>>>((const float4*)yo, scoresT, slot_of,
          (const float4*)xt, (const float4*)xs, (float4*)out, racc);
    }
  }
  finish_kernel<<<1, 64, 0, stream>>>(racc, out + (size_t)NTOK * TWOD);
}